// Round 1
// baseline (4512.445 us; speedup 1.0000x reference)
//
#include <hip/hip_runtime.h>

#define BN_EPS 1e-5f

__device__ __forceinline__ float fatomic_add(float* p, float v) {
    // HW global_atomic_add_f32 (plain atomicAdd(float*) may lower to a CAS loop)
    return unsafeAtomicAdd(p, v);
}

// ---------------- degree / norm ----------------
__global__ __launch_bounds__(256) void k_init_deg(float* deg, int n) {
    int i = blockIdx.x * 256 + threadIdx.x;
    if (i < n) deg[i] = 1.0f;   // self-loop weight
}

__global__ __launch_bounds__(256) void k_deg(const int* __restrict__ col,
                                             const float* __restrict__ ew,
                                             float* deg, int E) {
    int e = blockIdx.x * 256 + threadIdx.x;
    if (e < E) fatomic_add(&deg[col[e]], ew[e]);
}

__global__ __launch_bounds__(256) void k_dinv(float* deg, int n) {
    int i = blockIdx.x * 256 + threadIdx.x;
    if (i < n) deg[i] = rsqrtf(deg[i]);   // deg >= 1 always
}

// ---------------- GEMM: t = dinv .* (x @ W); acc = t (self-loop init) ------
__global__ __launch_bounds__(256) void k_gemm(const float* __restrict__ x,
                                              const float* __restrict__ W,
                                              const float* __restrict__ dinv,
                                              float* __restrict__ t,
                                              float* __restrict__ acc,
                                              int n) {
    __shared__ float Ws[64 * 64];
    __shared__ float xs[4][64];
    int tid = threadIdx.x;
    for (int i = tid; i < 4096; i += 256) Ws[i] = W[i];
    int row0 = blockIdx.x * 4;
    int rl = tid >> 6, f = tid & 63;
    int row = row0 + rl;
    if (row < n) xs[rl][f] = x[row * 64 + f];
    __syncthreads();
    if (row >= n) return;
    float a = 0.f;
#pragma unroll
    for (int k = 0; k < 64; ++k) a += xs[rl][k] * Ws[k * 64 + f];
    a *= dinv[row];
    int idx = row * 64 + f;
    t[idx] = a;
    acc[idx] = a;
}

// ---------------- edge scatter: acc[c] += w * t[r] ----------------
__global__ __launch_bounds__(256) void k_scatter(const int* __restrict__ rowi,
                                                 const int* __restrict__ coli,
                                                 const float* __restrict__ ew,
                                                 const float* __restrict__ t,
                                                 float* __restrict__ acc,
                                                 int E) {
    int gid = blockIdx.x * 256 + threadIdx.x;  // E*16 threads, float4 per thread
    if (gid >= E * 16) return;
    int e = gid >> 4, q = gid & 15;
    int r = rowi[e], c = coli[e];
    float w = ew[e];
    const float4* t4 = (const float4*)t;
    float4 v = t4[r * 16 + q];
    float* dst = acc + c * 64 + q * 4;
    fatomic_add(dst + 0, w * v.x);
    fatomic_add(dst + 1, w * v.y);
    fatomic_add(dst + 2, w * v.z);
    fatomic_add(dst + 3, w * v.w);
}

// ---------------- pointwise: h = BN(ReLU(dinv*acc + b)) ----------------
__global__ __launch_bounds__(256) void k_post(const float* __restrict__ acc,
                                              const float* __restrict__ dinv,
                                              const float* __restrict__ bias,
                                              const float* __restrict__ gam,
                                              const float* __restrict__ bet,
                                              const float* __restrict__ mu,
                                              const float* __restrict__ var,
                                              float* __restrict__ out,
                                              int n64, int do_relu) {
    int gid = blockIdx.x * 256 + threadIdx.x;
    if (gid >= n64) return;
    int nrow = gid >> 6, f = gid & 63;
    float val = dinv[nrow] * acc[gid] + bias[f];
    if (do_relu) val = fmaxf(val, 0.f);
    val = (val - mu[f]) * rsqrtf(var[f] + BN_EPS) * gam[f] + bet[f];
    out[gid] = val;
}

// ---------------- layer-3 pointwise + global_add_pool ----------------
__global__ __launch_bounds__(256) void k_post_pool(const float* __restrict__ acc,
                                                   const float* __restrict__ dinv,
                                                   const float* __restrict__ bias,
                                                   const float* __restrict__ gam,
                                                   const float* __restrict__ bet,
                                                   const float* __restrict__ mu,
                                                   const float* __restrict__ var,
                                                   const int* __restrict__ batch,
                                                   float* __restrict__ pooled,
                                                   int n64) {
    int gid = blockIdx.x * 256 + threadIdx.x;
    if (gid >= n64) return;
    int nrow = gid >> 6, f = gid & 63;
    float val = dinv[nrow] * acc[gid] + bias[f];   // no ReLU before bn3
    val = (val - mu[f]) * rsqrtf(var[f] + BN_EPS) * gam[f] + bet[f];
    fatomic_add(&pooled[batch[nrow] * 64 + f], val);
}

// ---------------- final: out[g] = ReLU(pooled[g]) @ Wfc + bfc ----------------
__global__ __launch_bounds__(128) void k_fc(const float* __restrict__ pooled,
                                            const float* __restrict__ Wfc,
                                            const float* __restrict__ bfc,
                                            float* __restrict__ out, int G) {
    int g = threadIdx.x;
    if (g >= G) return;
    float s = bfc[0];
#pragma unroll
    for (int f = 0; f < 64; ++f) s += fmaxf(pooled[g * 64 + f], 0.f) * Wfc[f];
    out[g] = s;
}

extern "C" void kernel_launch(void* const* d_in, const int* in_sizes, int n_in,
                              void* d_out, int out_size, void* d_ws, size_t ws_size,
                              hipStream_t stream) {
    const float* x    = (const float*)d_in[0];
    const int*   eidx = (const int*)d_in[1];
    const float* ew   = (const float*)d_in[2];
    const int*   batch= (const int*)d_in[3];
    const float* W1 = (const float*)d_in[4];
    const float* b1 = (const float*)d_in[5];
    const float* W2 = (const float*)d_in[6];
    const float* b2 = (const float*)d_in[7];
    const float* W3 = (const float*)d_in[8];
    const float* b3 = (const float*)d_in[9];
    const float* Wfc = (const float*)d_in[10];
    const float* bfc = (const float*)d_in[11];
    const float* g1 = (const float*)d_in[12];
    const float* be1 = (const float*)d_in[13];
    const float* m1 = (const float*)d_in[14];
    const float* v1 = (const float*)d_in[15];
    const float* g2 = (const float*)d_in[16];
    const float* be2 = (const float*)d_in[17];
    const float* m2 = (const float*)d_in[18];
    const float* v2 = (const float*)d_in[19];
    const float* g3 = (const float*)d_in[20];
    const float* be3 = (const float*)d_in[21];
    const float* m3 = (const float*)d_in[22];
    const float* v3 = (const float*)d_in[23];

    const int N = in_sizes[0] / 64;     // 100000
    const int E = in_sizes[1] / 2;      // 1600000
    const int G = out_size;             // 128
    const int* rowi = eidx;
    const int* coli = eidx + E;

    // workspace layout (bytes, 16B aligned)
    char* ws = (char*)d_ws;
    float* dinv   = (float*)ws;                                   // N floats
    size_t off = (size_t)((N * 4 + 255) & ~255);
    float* t      = (float*)(ws + off);                           // N*64 floats
    off += (size_t)N * 64 * 4;
    float* acc    = (float*)(ws + off);                           // N*64 floats
    off += (size_t)N * 64 * 4;
    float* pooled = (float*)(ws + off);                           // G*64 floats

    const int nblk  = (N + 255) / 256;
    const int n64   = N * 64;
    const int pblk  = (n64 + 255) / 256;
    const int eblk  = (E + 255) / 256;
    const int sblk  = (E * 16 + 255) / 256;

    // normalization coefficients (deg computed in-place into dinv)
    k_init_deg<<<nblk, 256, 0, stream>>>(dinv, N);
    k_deg<<<eblk, 256, 0, stream>>>(coli, ew, dinv, E);
    k_dinv<<<nblk, 256, 0, stream>>>(dinv, N);

    // ---- layer 1 ----
    k_gemm<<<(N + 3) / 4, 256, 0, stream>>>(x, W1, dinv, t, acc, N);
    k_scatter<<<sblk, 256, 0, stream>>>(rowi, coli, ew, t, acc, E);
    k_post<<<pblk, 256, 0, stream>>>(acc, dinv, b1, g1, be1, m1, v1, t, n64, 1);

    // ---- layer 2 ----
    k_gemm<<<(N + 3) / 4, 256, 0, stream>>>(t, W2, dinv, t, acc, N);
    k_scatter<<<sblk, 256, 0, stream>>>(rowi, coli, ew, t, acc, E);
    k_post<<<pblk, 256, 0, stream>>>(acc, dinv, b2, g2, be2, m2, v2, t, n64, 1);

    // ---- layer 3 + pool ----
    k_gemm<<<(N + 3) / 4, 256, 0, stream>>>(t, W3, dinv, t, acc, N);
    k_scatter<<<sblk, 256, 0, stream>>>(rowi, coli, ew, t, acc, E);
    hipMemsetAsync(pooled, 0, (size_t)G * 64 * 4, stream);
    k_post_pool<<<pblk, 256, 0, stream>>>(acc, dinv, b3, g3, be3, m3, v3, batch,
                                          pooled, n64);

    // ---- FC head ----
    k_fc<<<1, 128, 0, stream>>>(pooled, Wfc, bfc, (float*)d_out, G);
}

// Round 2
// 727.275 us; speedup vs baseline: 6.2046x; 6.2046x over previous
//
#include <hip/hip_runtime.h>

#define BN_EPS 1e-5f

__device__ __forceinline__ float fatomic_add(float* p, float v) {
    return unsafeAtomicAdd(p, v);  // HW global_atomic_add_f32
}

// ---------------- degree / histogram ----------------
__global__ __launch_bounds__(256) void k_init_deg(float* deg, int n) {
    int i = blockIdx.x * 256 + threadIdx.x;
    if (i < n) deg[i] = 1.0f;   // self-loop weight
}

__global__ __launch_bounds__(256) void k_deg_hist(const int* __restrict__ col,
                                                  const float* __restrict__ ew,
                                                  float* __restrict__ deg,
                                                  int* __restrict__ cnt, int E) {
    int e = blockIdx.x * 256 + threadIdx.x;
    if (e < E) {
        int c = col[e];
        fatomic_add(&deg[c], ew[e]);
        atomicAdd(&cnt[c], 1);
    }
}

__global__ __launch_bounds__(256) void k_dinv(float* deg, int n) {
    int i = blockIdx.x * 256 + threadIdx.x;
    if (i < n) deg[i] = rsqrtf(deg[i]);   // deg >= 1 always
}

// ---------------- exclusive scan (3-phase) ----------------
__global__ __launch_bounds__(256) void k_scan1(const int* __restrict__ cnt,
                                               int* __restrict__ local,
                                               int* __restrict__ bsum, int n) {
    __shared__ int sm[256];
    int tid = threadIdx.x;
    int i = blockIdx.x * 256 + tid;
    int v = (i < n) ? cnt[i] : 0;
    sm[tid] = v;
    __syncthreads();
    for (int off = 1; off < 256; off <<= 1) {
        int add = (tid >= off) ? sm[tid - off] : 0;
        __syncthreads();
        sm[tid] += add;
        __syncthreads();
    }
    if (i < n) local[i] = sm[tid] - v;          // exclusive
    if (tid == 255) bsum[blockIdx.x] = sm[255]; // block total
}

__global__ __launch_bounds__(512) void k_scan2(int* bsum, int nb) {
    __shared__ int sm[512];
    int tid = threadIdx.x;
    int v = (tid < nb) ? bsum[tid] : 0;
    sm[tid] = v;
    __syncthreads();
    for (int off = 1; off < 512; off <<= 1) {
        int add = (tid >= off) ? sm[tid - off] : 0;
        __syncthreads();
        sm[tid] += add;
        __syncthreads();
    }
    if (tid < nb) bsum[tid] = sm[tid] - v;      // exclusive
}

__global__ __launch_bounds__(256) void k_scan3(const int* __restrict__ local,
                                               const int* __restrict__ bsum,
                                               int* __restrict__ start,
                                               int n, int E) {
    int i = blockIdx.x * 256 + threadIdx.x;
    if (i < n) start[i] = local[i] + bsum[blockIdx.x];
    if (i == 0) start[n] = E;
}

// ---------------- CSR fill: csr[pos] = {row, bitcast(w)} ----------------
__global__ __launch_bounds__(256) void k_fill(const int* __restrict__ rowi,
                                              const int* __restrict__ coli,
                                              const float* __restrict__ ew,
                                              const int* __restrict__ start,
                                              int* __restrict__ cursor,
                                              int2* __restrict__ csr, int E) {
    int e = blockIdx.x * 256 + threadIdx.x;
    if (e < E) {
        int c = coli[e];
        int pos = start[c] + atomicAdd(&cursor[c], 1);
        csr[pos] = make_int2(rowi[e], __float_as_int(ew[e]));
    }
}

// ---------------- GEMM: t = dinv .* (x @ W), 16 rows/block ----------------
__global__ __launch_bounds__(256) void k_gemm(const float* __restrict__ x,
                                              const float* __restrict__ W,
                                              const float* __restrict__ dinv,
                                              float* __restrict__ t, int n) {
    __shared__ float Ws[64 * 64];
    __shared__ float xs[16][64];
    int tid = threadIdx.x;
    for (int i = tid; i < 4096; i += 256) Ws[i] = W[i];
    int row0 = blockIdx.x * 16;
    int nrows = min(16, n - row0);
    {
        const float4* xsrc = (const float4*)(x + (size_t)row0 * 64);
        float4* xdst = (float4*)&xs[0][0];
        if (tid < nrows * 16) xdst[tid] = xsrc[tid];
    }
    __syncthreads();
    int rl = tid >> 4;            // 0..15
    int f0 = (tid & 15) * 4;      // 0..60
    int row = row0 + rl;
    if (rl >= nrows) return;
    float a0 = 0.f, a1 = 0.f, a2 = 0.f, a3 = 0.f;
#pragma unroll
    for (int k = 0; k < 64; ++k) {
        float xv = xs[rl][k];
        const float* wr = &Ws[k * 64 + f0];
        a0 += xv * wr[0]; a1 += xv * wr[1]; a2 += xv * wr[2]; a3 += xv * wr[3];
    }
    float d = dinv[row];
    float4 o = make_float4(a0 * d, a1 * d, a2 * d, a3 * d);
    ((float4*)(t + (size_t)row * 64))[f0 >> 2] = o;
}

// ------- fused gather + post: h = BN(ReLU?(dinv*(self+Σ w·t[r]) + b)) -------
// mode 0: ReLU+BN -> out ; mode 1: BN -> pooled (block-reduced atomics)
__global__ __launch_bounds__(256) void k_gather(const int2* __restrict__ csr,
                                                const int* __restrict__ start,
                                                const float* __restrict__ t,
                                                const float* __restrict__ dinv,
                                                const float* __restrict__ bias,
                                                const float* __restrict__ gam,
                                                const float* __restrict__ bet,
                                                const float* __restrict__ mu,
                                                const float* __restrict__ var,
                                                float* __restrict__ out,
                                                const int* __restrict__ batch,
                                                float* __restrict__ pooled,
                                                int n, int mode) {
    __shared__ float vals[4][64];
    __shared__ int bids[4];
    int w = threadIdx.x >> 6, f = threadIdx.x & 63;
    int node = blockIdx.x * 4 + w;
    int valid = node < n;
    float val = 0.f;
    if (valid) {
        float acc = t[(size_t)node * 64 + f];      // self-loop (pre-scaled)
        int s = start[node], eend = start[node + 1];
        int e = s;
        int even = (eend - s) & ~1;
        for (; e < s + even; e += 2) {             // 2x unroll for MLP overlap
            int2 ea = csr[e];
            int2 eb = csr[e + 1];
            float ta = t[(size_t)ea.x * 64 + f];
            float tb = t[(size_t)eb.x * 64 + f];
            acc = fmaf(__int_as_float(ea.y), ta, acc);
            acc = fmaf(__int_as_float(eb.y), tb, acc);
        }
        if (e < eend) {
            int2 ea = csr[e];
            acc = fmaf(__int_as_float(ea.y), t[(size_t)ea.x * 64 + f], acc);
        }
        val = dinv[node] * acc + bias[f];
        if (mode == 0) val = fmaxf(val, 0.f);
        val = (val - mu[f]) * rsqrtf(var[f] + BN_EPS) * gam[f] + bet[f];
        if (mode == 0) out[(size_t)node * 64 + f] = val;
    }
    if (mode == 1) {
        vals[w][f] = valid ? val : 0.f;
        if (f == 0) bids[w] = valid ? batch[node] : -1;
        __syncthreads();
        if (w == 0) {
            float s2 = vals[0][f];
            int cur = bids[0];
            for (int i = 1; i < 4; ++i) {
                if (bids[i] == cur) {
                    s2 += vals[i][f];
                } else {
                    if (cur >= 0) fatomic_add(&pooled[cur * 64 + f], s2);
                    cur = bids[i];
                    s2 = vals[i][f];
                }
            }
            if (cur >= 0) fatomic_add(&pooled[cur * 64 + f], s2);
        }
    }
}

// ---------------- final: out[g] = ReLU(pooled[g]) @ Wfc + bfc ----------------
__global__ __launch_bounds__(128) void k_fc(const float* __restrict__ pooled,
                                            const float* __restrict__ Wfc,
                                            const float* __restrict__ bfc,
                                            float* __restrict__ out, int G) {
    int g = threadIdx.x;
    if (g >= G) return;
    float s = bfc[0];
#pragma unroll
    for (int f = 0; f < 64; ++f) s += fmaxf(pooled[g * 64 + f], 0.f) * Wfc[f];
    out[g] = s;
}

extern "C" void kernel_launch(void* const* d_in, const int* in_sizes, int n_in,
                              void* d_out, int out_size, void* d_ws, size_t ws_size,
                              hipStream_t stream) {
    const float* x    = (const float*)d_in[0];
    const int*   eidx = (const int*)d_in[1];
    const float* ew   = (const float*)d_in[2];
    const int*   batch= (const int*)d_in[3];
    const float* W1 = (const float*)d_in[4];
    const float* b1 = (const float*)d_in[5];
    const float* W2 = (const float*)d_in[6];
    const float* b2 = (const float*)d_in[7];
    const float* W3 = (const float*)d_in[8];
    const float* b3 = (const float*)d_in[9];
    const float* Wfc = (const float*)d_in[10];
    const float* bfc = (const float*)d_in[11];
    const float* g1 = (const float*)d_in[12];
    const float* be1 = (const float*)d_in[13];
    const float* m1 = (const float*)d_in[14];
    const float* v1 = (const float*)d_in[15];
    const float* g2 = (const float*)d_in[16];
    const float* be2 = (const float*)d_in[17];
    const float* m2 = (const float*)d_in[18];
    const float* v2 = (const float*)d_in[19];
    const float* g3 = (const float*)d_in[20];
    const float* be3 = (const float*)d_in[21];
    const float* m3 = (const float*)d_in[22];
    const float* v3 = (const float*)d_in[23];

    const int N = in_sizes[0] / 64;     // 100000
    const int E = in_sizes[1] / 2;      // 1600000
    const int G = out_size;             // 128
    const int* rowi = eidx;
    const int* coli = eidx + E;

    // -------- workspace layout (256B aligned) --------
    char* ws = (char*)d_ws;
    size_t off = 0;
    auto alloc = [&](size_t bytes) {
        char* p = ws + off;
        off += (bytes + 255) & ~(size_t)255;
        return p;
    };
    float* dinv   = (float*)alloc((size_t)N * 4);
    int*   cnt    = (int*)  alloc((size_t)N * 4);     // histogram, then cursor
    int*   local  = (int*)  alloc((size_t)N * 4);
    int*   bsum   = (int*)  alloc(512 * 4);
    int*   start  = (int*)  alloc((size_t)(N + 1) * 4);
    int2*  csr    = (int2*) alloc((size_t)E * 8);
    float* t      = (float*)alloc((size_t)N * 64 * 4);
    float* h      = (float*)alloc((size_t)N * 64 * 4);
    float* pooled = (float*)alloc((size_t)G * 64 * 4);

    const int nblk = (N + 255) / 256;
    const int eblk = (E + 255) / 256;
    const int gblk = (N + 3) / 4;
    const int mblk = (N + 15) / 16;

    // -------- CSR build + normalization --------
    k_init_deg<<<nblk, 256, 0, stream>>>(dinv, N);
    hipMemsetAsync(cnt, 0, (size_t)N * 4, stream);
    k_deg_hist<<<eblk, 256, 0, stream>>>(coli, ew, dinv, cnt, E);
    k_dinv<<<nblk, 256, 0, stream>>>(dinv, N);
    k_scan1<<<nblk, 256, 0, stream>>>(cnt, local, bsum, N);
    k_scan2<<<1, 512, 0, stream>>>(bsum, nblk);
    k_scan3<<<nblk, 256, 0, stream>>>(local, bsum, start, N, E);
    hipMemsetAsync(cnt, 0, (size_t)N * 4, stream);   // reuse as cursor
    k_fill<<<eblk, 256, 0, stream>>>(rowi, coli, ew, start, cnt, csr, E);

    // -------- layer 1 --------
    k_gemm<<<mblk, 256, 0, stream>>>(x, W1, dinv, t, N);
    k_gather<<<gblk, 256, 0, stream>>>(csr, start, t, dinv, b1, g1, be1, m1, v1,
                                       h, batch, pooled, N, 0);
    // -------- layer 2 --------
    k_gemm<<<mblk, 256, 0, stream>>>(h, W2, dinv, t, N);
    k_gather<<<gblk, 256, 0, stream>>>(csr, start, t, dinv, b2, g2, be2, m2, v2,
                                       h, batch, pooled, N, 0);
    // -------- layer 3 + pool --------
    k_gemm<<<mblk, 256, 0, stream>>>(h, W3, dinv, t, N);
    hipMemsetAsync(pooled, 0, (size_t)G * 64 * 4, stream);
    k_gather<<<gblk, 256, 0, stream>>>(csr, start, t, dinv, b3, g3, be3, m3, v3,
                                       h, batch, pooled, N, 1);
    // -------- FC head --------
    k_fc<<<1, 128, 0, stream>>>(pooled, Wfc, bfc, (float*)d_out, G);
}

// Round 3
// 598.355 us; speedup vs baseline: 7.5414x; 1.2155x over previous
//
#include <hip/hip_runtime.h>

#define BN_EPS 1e-5f
#define FIXP 1048576.0f          // 2^20 fixed-point scale for edge weights
#define FIXP_INV (1.0f / 1048576.0f)

__device__ __forceinline__ float fatomic_add(float* p, float v) {
    return unsafeAtomicAdd(p, v);  // HW global_atomic_add_f32
}

// ------- histogram + deg + rank in ONE u64 atomic per edge -------
// cnt64[c] accumulates (1<<32) | fix(w); returned old>>32 = edge's rank.
__global__ __launch_bounds__(256) void k_hist_rank(const int* __restrict__ col,
                                                   const float* __restrict__ ew,
                                                   unsigned long long* __restrict__ cnt64,
                                                   int* __restrict__ rank, int E) {
    int e = blockIdx.x * 256 + threadIdx.x;
    if (e < E) {
        int c = col[e];
        unsigned long long pay =
            (1ULL << 32) | (unsigned long long)__float2uint_rn(ew[e] * FIXP);
        unsigned long long old = atomicAdd(&cnt64[c], pay);
        rank[e] = (int)(old >> 32);
    }
}

// dinv[i] = rsqrt(1 + deg_fixed * 2^-20)   (self-loop weight folded in)
__global__ __launch_bounds__(256) void k_dinv(const unsigned long long* __restrict__ cnt64,
                                              float* __restrict__ dinv, int n) {
    int i = blockIdx.x * 256 + threadIdx.x;
    if (i < n) {
        float deg = 1.0f + (float)(unsigned int)(cnt64[i] & 0xffffffffULL) * FIXP_INV;
        dinv[i] = rsqrtf(deg);
    }
}

// ---------------- exclusive scan (3-phase) over high-32 counts ----------------
__global__ __launch_bounds__(256) void k_scan1(const unsigned long long* __restrict__ cnt64,
                                               int* __restrict__ local,
                                               int* __restrict__ bsum, int n) {
    __shared__ int sm[256];
    int tid = threadIdx.x;
    int i = blockIdx.x * 256 + tid;
    int v = (i < n) ? (int)(cnt64[i] >> 32) : 0;
    sm[tid] = v;
    __syncthreads();
    for (int off = 1; off < 256; off <<= 1) {
        int add = (tid >= off) ? sm[tid - off] : 0;
        __syncthreads();
        sm[tid] += add;
        __syncthreads();
    }
    if (i < n) local[i] = sm[tid] - v;          // exclusive
    if (tid == 255) bsum[blockIdx.x] = sm[255]; // block total
}

__global__ __launch_bounds__(512) void k_scan2(int* bsum, int nb) {
    __shared__ int sm[512];
    int tid = threadIdx.x;
    int v = (tid < nb) ? bsum[tid] : 0;
    sm[tid] = v;
    __syncthreads();
    for (int off = 1; off < 512; off <<= 1) {
        int add = (tid >= off) ? sm[tid - off] : 0;
        __syncthreads();
        sm[tid] += add;
        __syncthreads();
    }
    if (tid < nb) bsum[tid] = sm[tid] - v;      // exclusive
}

__global__ __launch_bounds__(256) void k_scan3(const int* __restrict__ local,
                                               const int* __restrict__ bsum,
                                               int* __restrict__ start,
                                               int n, int E) {
    int i = blockIdx.x * 256 + threadIdx.x;
    if (i < n) start[i] = local[i] + bsum[blockIdx.x];
    if (i == 0) start[n] = E;
}

// ---------------- CSR fill (atomic-free): csr[start[c]+rank[e]] ----------------
__global__ __launch_bounds__(256) void k_fill(const int* __restrict__ rowi,
                                              const int* __restrict__ coli,
                                              const float* __restrict__ ew,
                                              const int* __restrict__ start,
                                              const int* __restrict__ rank,
                                              int2* __restrict__ csr, int E) {
    int e = blockIdx.x * 256 + threadIdx.x;
    if (e < E) {
        int c = coli[e];
        csr[start[c] + rank[e]] = make_int2(rowi[e], __float_as_int(ew[e]));
    }
}

// ---------------- GEMM: t = dinv .* (x @ W), 16 rows/block ----------------
__global__ __launch_bounds__(256) void k_gemm(const float* __restrict__ x,
                                              const float* __restrict__ W,
                                              const float* __restrict__ dinv,
                                              float* __restrict__ t, int n) {
    __shared__ float Ws[64 * 64];
    __shared__ float xs[16][64];
    int tid = threadIdx.x;
    for (int i = tid; i < 4096; i += 256) Ws[i] = W[i];
    int row0 = blockIdx.x * 16;
    int nrows = min(16, n - row0);
    {
        const float4* xsrc = (const float4*)(x + (size_t)row0 * 64);
        float4* xdst = (float4*)&xs[0][0];
        if (tid < nrows * 16) xdst[tid] = xsrc[tid];
    }
    __syncthreads();
    int rl = tid >> 4;            // 0..15
    int f0 = (tid & 15) * 4;      // 0..60
    int row = row0 + rl;
    if (rl >= nrows) return;
    float a0 = 0.f, a1 = 0.f, a2 = 0.f, a3 = 0.f;
#pragma unroll
    for (int k = 0; k < 64; ++k) {
        float xv = xs[rl][k];
        const float* wr = &Ws[k * 64 + f0];
        a0 += xv * wr[0]; a1 += xv * wr[1]; a2 += xv * wr[2]; a3 += xv * wr[3];
    }
    float d = dinv[row];
    float4 o = make_float4(a0 * d, a1 * d, a2 * d, a3 * d);
    ((float4*)(t + (size_t)row * 64))[f0 >> 2] = o;
}

// ------- fused gather + post: h = BN(ReLU?(dinv*(self+Σ w·t[r]) + b)) -------
// mode 0: ReLU+BN -> out ; mode 1: BN -> pooled (block-reduced atomics)
__global__ __launch_bounds__(256) void k_gather(const int2* __restrict__ csr,
                                                const int* __restrict__ start,
                                                const float* __restrict__ t,
                                                const float* __restrict__ dinv,
                                                const float* __restrict__ bias,
                                                const float* __restrict__ gam,
                                                const float* __restrict__ bet,
                                                const float* __restrict__ mu,
                                                const float* __restrict__ var,
                                                float* __restrict__ out,
                                                const int* __restrict__ batch,
                                                float* __restrict__ pooled,
                                                int n, int mode) {
    __shared__ float vals[4][64];
    __shared__ int bids[4];
    int w = threadIdx.x >> 6, f = threadIdx.x & 63;
    int node = blockIdx.x * 4 + w;
    int valid = node < n;
    float val = 0.f;
    if (valid) {
        float acc = t[(size_t)node * 64 + f];      // self-loop (pre-scaled)
        int s = start[node], eend = start[node + 1];
        int e = s;
        int even = (eend - s) & ~1;
        for (; e < s + even; e += 2) {             // 2x unroll: 2 indep chains
            int2 ea = csr[e];
            int2 eb = csr[e + 1];
            float ta = t[(size_t)ea.x * 64 + f];
            float tb = t[(size_t)eb.x * 64 + f];
            acc = fmaf(__int_as_float(ea.y), ta, acc);
            acc = fmaf(__int_as_float(eb.y), tb, acc);
        }
        if (e < eend) {
            int2 ea = csr[e];
            acc = fmaf(__int_as_float(ea.y), t[(size_t)ea.x * 64 + f], acc);
        }
        val = dinv[node] * acc + bias[f];
        if (mode == 0) val = fmaxf(val, 0.f);
        val = (val - mu[f]) * rsqrtf(var[f] + BN_EPS) * gam[f] + bet[f];
        if (mode == 0) out[(size_t)node * 64 + f] = val;
    }
    if (mode == 1) {
        vals[w][f] = valid ? val : 0.f;
        if (f == 0) bids[w] = valid ? batch[node] : -1;
        __syncthreads();
        if (w == 0) {
            float s2 = vals[0][f];
            int cur = bids[0];
            for (int i = 1; i < 4; ++i) {
                if (bids[i] == cur) {
                    s2 += vals[i][f];
                } else {
                    if (cur >= 0) fatomic_add(&pooled[cur * 64 + f], s2);
                    cur = bids[i];
                    s2 = vals[i][f];
                }
            }
            if (cur >= 0) fatomic_add(&pooled[cur * 64 + f], s2);
        }
    }
}

// ---------------- final: out[g] = ReLU(pooled[g]) @ Wfc + bfc ----------------
__global__ __launch_bounds__(128) void k_fc(const float* __restrict__ pooled,
                                            const float* __restrict__ Wfc,
                                            const float* __restrict__ bfc,
                                            float* __restrict__ out, int G) {
    int g = threadIdx.x;
    if (g >= G) return;
    float s = bfc[0];
#pragma unroll
    for (int f = 0; f < 64; ++f) s += fmaxf(pooled[g * 64 + f], 0.f) * Wfc[f];
    out[g] = s;
}

extern "C" void kernel_launch(void* const* d_in, const int* in_sizes, int n_in,
                              void* d_out, int out_size, void* d_ws, size_t ws_size,
                              hipStream_t stream) {
    const float* x    = (const float*)d_in[0];
    const int*   eidx = (const int*)d_in[1];
    const float* ew   = (const float*)d_in[2];
    const int*   batch= (const int*)d_in[3];
    const float* W1 = (const float*)d_in[4];
    const float* b1 = (const float*)d_in[5];
    const float* W2 = (const float*)d_in[6];
    const float* b2 = (const float*)d_in[7];
    const float* W3 = (const float*)d_in[8];
    const float* b3 = (const float*)d_in[9];
    const float* Wfc = (const float*)d_in[10];
    const float* bfc = (const float*)d_in[11];
    const float* g1 = (const float*)d_in[12];
    const float* be1 = (const float*)d_in[13];
    const float* m1 = (const float*)d_in[14];
    const float* v1 = (const float*)d_in[15];
    const float* g2 = (const float*)d_in[16];
    const float* be2 = (const float*)d_in[17];
    const float* m2 = (const float*)d_in[18];
    const float* v2 = (const float*)d_in[19];
    const float* g3 = (const float*)d_in[20];
    const float* be3 = (const float*)d_in[21];
    const float* m3 = (const float*)d_in[22];
    const float* v3 = (const float*)d_in[23];

    const int N = in_sizes[0] / 64;     // 100000
    const int E = in_sizes[1] / 2;      // 1600000
    const int G = out_size;             // 128
    const int* rowi = eidx;
    const int* coli = eidx + E;

    // -------- workspace layout (256B aligned) --------
    char* ws = (char*)d_ws;
    size_t off = 0;
    auto alloc = [&](size_t bytes) {
        char* p = ws + off;
        off += (bytes + 255) & ~(size_t)255;
        return p;
    };
    float* dinv   = (float*)alloc((size_t)N * 4);
    unsigned long long* cnt64 = (unsigned long long*)alloc((size_t)N * 8);
    int*   local  = (int*)  alloc((size_t)N * 4);
    int*   bsum   = (int*)  alloc(512 * 4);
    int*   start  = (int*)  alloc((size_t)(N + 1) * 4);
    int2*  csr    = (int2*) alloc((size_t)E * 8);
    float* t      = (float*)alloc((size_t)N * 64 * 4);
    float* h      = (float*)alloc((size_t)N * 64 * 4);
    float* pooled = (float*)alloc((size_t)G * 64 * 4);
    int*   rank   = (int*)h;   // rank (E*4 = 6.4MB) lives in h, dead until layer 1

    const int nblk = (N + 255) / 256;
    const int eblk = (E + 255) / 256;
    const int gblk = (N + 3) / 4;
    const int mblk = (N + 15) / 16;

    // -------- CSR build + normalization --------
    hipMemsetAsync(cnt64, 0, (size_t)N * 8, stream);
    k_hist_rank<<<eblk, 256, 0, stream>>>(coli, ew, cnt64, rank, E);
    k_dinv<<<nblk, 256, 0, stream>>>(cnt64, dinv, N);
    k_scan1<<<nblk, 256, 0, stream>>>(cnt64, local, bsum, N);
    k_scan2<<<1, 512, 0, stream>>>(bsum, nblk);
    k_scan3<<<nblk, 256, 0, stream>>>(local, bsum, start, N, E);
    k_fill<<<eblk, 256, 0, stream>>>(rowi, coli, ew, start, rank, csr, E);

    // -------- layer 1 --------
    k_gemm<<<mblk, 256, 0, stream>>>(x, W1, dinv, t, N);
    k_gather<<<gblk, 256, 0, stream>>>(csr, start, t, dinv, b1, g1, be1, m1, v1,
                                       h, batch, pooled, N, 0);
    // -------- layer 2 --------
    k_gemm<<<mblk, 256, 0, stream>>>(h, W2, dinv, t, N);
    k_gather<<<gblk, 256, 0, stream>>>(csr, start, t, dinv, b2, g2, be2, m2, v2,
                                       h, batch, pooled, N, 0);
    // -------- layer 3 + pool --------
    k_gemm<<<mblk, 256, 0, stream>>>(h, W3, dinv, t, N);
    hipMemsetAsync(pooled, 0, (size_t)G * 64 * 4, stream);
    k_gather<<<gblk, 256, 0, stream>>>(csr, start, t, dinv, b3, g3, be3, m3, v3,
                                       h, batch, pooled, N, 1);
    // -------- FC head --------
    k_fc<<<1, 128, 0, stream>>>(pooled, Wfc, bfc, (float*)d_out, G);
}

// Round 4
// 535.907 us; speedup vs baseline: 8.4202x; 1.1165x over previous
//
#include <hip/hip_runtime.h>
#include <hip/hip_fp16.h>

#define BN_EPS 1e-5f
#define FIXP 1048576.0f          // 2^20 fixed-point scale for edge weights
#define FIXP_INV (1.0f / 1048576.0f)

__device__ __forceinline__ float fatomic_add(float* p, float v) {
    return unsafeAtomicAdd(p, v);  // HW global_atomic_add_f32
}

// ------- histogram + deg + rank in ONE u64 atomic per edge -------
__global__ __launch_bounds__(256) void k_hist_rank(const int* __restrict__ col,
                                                   const float* __restrict__ ew,
                                                   unsigned long long* __restrict__ cnt64,
                                                   int* __restrict__ rank, int E) {
    int e = blockIdx.x * 256 + threadIdx.x;
    if (e < E) {
        int c = col[e];
        unsigned long long pay =
            (1ULL << 32) | (unsigned long long)__float2uint_rn(ew[e] * FIXP);
        unsigned long long old = atomicAdd(&cnt64[c], pay);
        rank[e] = (int)(old >> 32);
    }
}

// ---------------- scan phase 1 (+ fused dinv) ----------------
__global__ __launch_bounds__(256) void k_scan1(const unsigned long long* __restrict__ cnt64,
                                               int* __restrict__ local,
                                               int* __restrict__ bsum,
                                               float* __restrict__ dinv, int n) {
    __shared__ int sm[256];
    int tid = threadIdx.x;
    int i = blockIdx.x * 256 + tid;
    unsigned long long cv = (i < n) ? cnt64[i] : 0ULL;
    int v = (int)(cv >> 32);
    if (i < n) {
        float deg = 1.0f + (float)(unsigned int)(cv & 0xffffffffULL) * FIXP_INV;
        dinv[i] = rsqrtf(deg);
    }
    sm[tid] = v;
    __syncthreads();
    for (int off = 1; off < 256; off <<= 1) {
        int add = (tid >= off) ? sm[tid - off] : 0;
        __syncthreads();
        sm[tid] += add;
        __syncthreads();
    }
    if (i < n) local[i] = sm[tid] - v;          // exclusive
    if (tid == 255) bsum[blockIdx.x] = sm[255]; // block total
}

__global__ __launch_bounds__(512) void k_scan2(int* bsum, int nb) {
    __shared__ int sm[512];
    int tid = threadIdx.x;
    int v = (tid < nb) ? bsum[tid] : 0;
    sm[tid] = v;
    __syncthreads();
    for (int off = 1; off < 512; off <<= 1) {
        int add = (tid >= off) ? sm[tid - off] : 0;
        __syncthreads();
        sm[tid] += add;
        __syncthreads();
    }
    if (tid < nb) bsum[tid] = sm[tid] - v;      // exclusive
}

__global__ __launch_bounds__(256) void k_scan3(const int* __restrict__ local,
                                               const int* __restrict__ bsum,
                                               int* __restrict__ start,
                                               int n, int E) {
    int i = blockIdx.x * 256 + threadIdx.x;
    if (i < n) start[i] = local[i] + bsum[blockIdx.x];
    if (i == 0) start[n] = E;
}

// ---------------- CSR fill (atomic-free) ----------------
__global__ __launch_bounds__(256) void k_fill(const int* __restrict__ rowi,
                                              const int* __restrict__ coli,
                                              const float* __restrict__ ew,
                                              const int* __restrict__ start,
                                              const int* __restrict__ rank,
                                              int2* __restrict__ csr, int E) {
    int e = blockIdx.x * 256 + threadIdx.x;
    if (e < E) {
        int c = coli[e];
        csr[start[c] + rank[e]] = make_int2(rowi[e], __float_as_int(ew[e]));
    }
}

// ------- GEMM: t_h = fp16( dinv .* (x @ W) ), 16 rows/block -------
__global__ __launch_bounds__(256) void k_gemm(const float* __restrict__ x,
                                              const float* __restrict__ W,
                                              const float* __restrict__ dinv,
                                              __half* __restrict__ th, int n) {
    __shared__ float Ws[64 * 64];
    __shared__ float xs[16][64];
    int tid = threadIdx.x;
    for (int i = tid; i < 4096; i += 256) Ws[i] = W[i];
    int row0 = blockIdx.x * 16;
    int nrows = min(16, n - row0);
    {
        const float4* xsrc = (const float4*)(x + (size_t)row0 * 64);
        float4* xdst = (float4*)&xs[0][0];
        if (tid < nrows * 16) xdst[tid] = xsrc[tid];
    }
    __syncthreads();
    int rl = tid >> 4;            // 0..15
    int f0 = (tid & 15) * 4;      // 0..60
    int row = row0 + rl;
    if (rl >= nrows) return;
    float a0 = 0.f, a1 = 0.f, a2 = 0.f, a3 = 0.f;
#pragma unroll
    for (int k = 0; k < 64; ++k) {
        float xv = xs[rl][k];
        const float* wr = &Ws[k * 64 + f0];
        a0 += xv * wr[0]; a1 += xv * wr[1]; a2 += xv * wr[2]; a3 += xv * wr[3];
    }
    float d = dinv[row];
    union { __half2 h2[2]; int2 i2; } u;
    u.h2[0] = __floats2half2_rn(a0 * d, a1 * d);
    u.h2[1] = __floats2half2_rn(a2 * d, a3 * d);
    ((int2*)th)[((size_t)row * 64 + f0) >> 2] = u.i2;
}

// ------- fused gather + post: h = BN(ReLU?(dinv*(self+Σ w·t[r]) + b)) -------
// mode 0: ReLU+BN -> out ; mode 1: BN -> pooled (block-reduced atomics)
__global__ __launch_bounds__(256) void k_gather(const int2* __restrict__ csr,
                                                const int* __restrict__ start,
                                                const __half* __restrict__ th,
                                                const float* __restrict__ dinv,
                                                const float* __restrict__ bias,
                                                const float* __restrict__ gam,
                                                const float* __restrict__ bet,
                                                const float* __restrict__ mu,
                                                const float* __restrict__ var,
                                                float* __restrict__ out,
                                                const int* __restrict__ batch,
                                                float* __restrict__ pooled,
                                                int n, int mode) {
    __shared__ float vals[4][64];
    __shared__ int bids[4];
    int w = threadIdx.x >> 6, f = threadIdx.x & 63;
    int node = blockIdx.x * 4 + w;
    int valid = node < n;
    float val = 0.f;
    if (valid) {
        float acc0 = __half2float(th[(size_t)node * 64 + f]);  // self-loop
        float acc1 = 0.f, acc2 = 0.f, acc3 = 0.f;
        int s = start[node], eend = start[node + 1];
        int e = s;
        for (; e + 3 < eend; e += 4) {           // 4 independent load chains
            int2 e0 = csr[e];
            int2 e1 = csr[e + 1];
            int2 e2 = csr[e + 2];
            int2 e3 = csr[e + 3];
            float t0 = __half2float(th[(size_t)e0.x * 64 + f]);
            float t1 = __half2float(th[(size_t)e1.x * 64 + f]);
            float t2 = __half2float(th[(size_t)e2.x * 64 + f]);
            float t3 = __half2float(th[(size_t)e3.x * 64 + f]);
            acc0 = fmaf(__int_as_float(e0.y), t0, acc0);
            acc1 = fmaf(__int_as_float(e1.y), t1, acc1);
            acc2 = fmaf(__int_as_float(e2.y), t2, acc2);
            acc3 = fmaf(__int_as_float(e3.y), t3, acc3);
        }
        for (; e < eend; ++e) {
            int2 ea = csr[e];
            acc0 = fmaf(__int_as_float(ea.y),
                        __half2float(th[(size_t)ea.x * 64 + f]), acc0);
        }
        float acc = (acc0 + acc1) + (acc2 + acc3);
        val = dinv[node] * acc + bias[f];
        if (mode == 0) val = fmaxf(val, 0.f);
        val = (val - mu[f]) * rsqrtf(var[f] + BN_EPS) * gam[f] + bet[f];
        if (mode == 0) out[(size_t)node * 64 + f] = val;
    }
    if (mode == 1) {
        vals[w][f] = valid ? val : 0.f;
        if (f == 0) bids[w] = valid ? batch[node] : -1;
        __syncthreads();
        if (w == 0) {
            float s2 = vals[0][f];
            int cur = bids[0];
            for (int i = 1; i < 4; ++i) {
                if (bids[i] == cur) {
                    s2 += vals[i][f];
                } else {
                    if (cur >= 0) fatomic_add(&pooled[cur * 64 + f], s2);
                    cur = bids[i];
                    s2 = vals[i][f];
                }
            }
            if (cur >= 0) fatomic_add(&pooled[cur * 64 + f], s2);
        }
    }
}

// ---------------- final: out[g] = ReLU(pooled[g]) @ Wfc + bfc ----------------
__global__ __launch_bounds__(128) void k_fc(const float* __restrict__ pooled,
                                            const float* __restrict__ Wfc,
                                            const float* __restrict__ bfc,
                                            float* __restrict__ out, int G) {
    int g = threadIdx.x;
    if (g >= G) return;
    float s = bfc[0];
#pragma unroll
    for (int f = 0; f < 64; ++f) s += fmaxf(pooled[g * 64 + f], 0.f) * Wfc[f];
    out[g] = s;
}

extern "C" void kernel_launch(void* const* d_in, const int* in_sizes, int n_in,
                              void* d_out, int out_size, void* d_ws, size_t ws_size,
                              hipStream_t stream) {
    const float* x    = (const float*)d_in[0];
    const int*   eidx = (const int*)d_in[1];
    const float* ew   = (const float*)d_in[2];
    const int*   batch= (const int*)d_in[3];
    const float* W1 = (const float*)d_in[4];
    const float* b1 = (const float*)d_in[5];
    const float* W2 = (const float*)d_in[6];
    const float* b2 = (const float*)d_in[7];
    const float* W3 = (const float*)d_in[8];
    const float* b3 = (const float*)d_in[9];
    const float* Wfc = (const float*)d_in[10];
    const float* bfc = (const float*)d_in[11];
    const float* g1 = (const float*)d_in[12];
    const float* be1 = (const float*)d_in[13];
    const float* m1 = (const float*)d_in[14];
    const float* v1 = (const float*)d_in[15];
    const float* g2 = (const float*)d_in[16];
    const float* be2 = (const float*)d_in[17];
    const float* m2 = (const float*)d_in[18];
    const float* v2 = (const float*)d_in[19];
    const float* g3 = (const float*)d_in[20];
    const float* be3 = (const float*)d_in[21];
    const float* m3 = (const float*)d_in[22];
    const float* v3 = (const float*)d_in[23];

    const int N = in_sizes[0] / 64;     // 100000
    const int E = in_sizes[1] / 2;      // 1600000
    const int G = out_size;             // 128
    const int* rowi = eidx;
    const int* coli = eidx + E;

    // -------- workspace layout (256B aligned) --------
    char* ws = (char*)d_ws;
    size_t off = 0;
    auto alloc = [&](size_t bytes) {
        char* p = ws + off;
        off += (bytes + 255) & ~(size_t)255;
        return p;
    };
    float* dinv   = (float*)alloc((size_t)N * 4);
    unsigned long long* cnt64 = (unsigned long long*)alloc((size_t)N * 8);
    int*   local  = (int*)  alloc((size_t)N * 4);
    int*   bsum   = (int*)  alloc(512 * 4);
    int*   start  = (int*)  alloc((size_t)(N + 1) * 4);
    int2*  csr    = (int2*) alloc((size_t)E * 8);
    __half* th    = (__half*)alloc((size_t)N * 64 * 2);
    float* h      = (float*)alloc((size_t)N * 64 * 4);
    float* pooled = (float*)alloc((size_t)G * 64 * 4);
    int*   rank   = (int*)h;   // rank (6.4MB) lives in h, dead until layer 1

    const int nblk = (N + 255) / 256;
    const int eblk = (E + 255) / 256;
    const int gblk = (N + 3) / 4;
    const int mblk = (N + 15) / 16;

    // -------- CSR build + normalization --------
    hipMemsetAsync(cnt64, 0, (size_t)N * 8, stream);
    k_hist_rank<<<eblk, 256, 0, stream>>>(coli, ew, cnt64, rank, E);
    k_scan1<<<nblk, 256, 0, stream>>>(cnt64, local, bsum, dinv, N);
    k_scan2<<<1, 512, 0, stream>>>(bsum, nblk);
    k_scan3<<<nblk, 256, 0, stream>>>(local, bsum, start, N, E);
    k_fill<<<eblk, 256, 0, stream>>>(rowi, coli, ew, start, rank, csr, E);

    // -------- layer 1 --------
    k_gemm<<<mblk, 256, 0, stream>>>(x, W1, dinv, th, N);
    k_gather<<<gblk, 256, 0, stream>>>(csr, start, th, dinv, b1, g1, be1, m1, v1,
                                       h, batch, pooled, N, 0);
    // -------- layer 2 --------
    k_gemm<<<mblk, 256, 0, stream>>>(h, W2, dinv, th, N);
    k_gather<<<gblk, 256, 0, stream>>>(csr, start, th, dinv, b2, g2, be2, m2, v2,
                                       h, batch, pooled, N, 0);
    // -------- layer 3 + pool --------
    k_gemm<<<mblk, 256, 0, stream>>>(h, W3, dinv, th, N);
    hipMemsetAsync(pooled, 0, (size_t)G * 64 * 4, stream);
    k_gather<<<gblk, 256, 0, stream>>>(csr, start, th, dinv, b3, g3, be3, m3, v3,
                                       h, batch, pooled, N, 1);
    // -------- FC head --------
    k_fc<<<1, 128, 0, stream>>>(pooled, Wfc, bfc, (float*)d_out, G);
}

// Round 5
// 505.816 us; speedup vs baseline: 8.9211x; 1.0595x over previous
//
#include <hip/hip_runtime.h>
#include <hip/hip_fp16.h>

#define BN_EPS 1e-5f
#define FIXP 1048576.0f          // 2^20 fixed-point scale for edge weights
#define FIXP_INV (1.0f / 1048576.0f)

__device__ __forceinline__ float fatomic_add(float* p, float v) {
    return unsafeAtomicAdd(p, v);  // HW global_atomic_add_f32
}

// ------- histogram + deg + rank in ONE u64 atomic per edge -------
__global__ __launch_bounds__(256) void k_hist_rank(const int* __restrict__ col,
                                                   const float* __restrict__ ew,
                                                   unsigned long long* __restrict__ cnt64,
                                                   int* __restrict__ rank, int E) {
    int e = blockIdx.x * 256 + threadIdx.x;
    if (e < E) {
        int c = col[e];
        unsigned long long pay =
            (1ULL << 32) | (unsigned long long)__float2uint_rn(ew[e] * FIXP);
        unsigned long long old = atomicAdd(&cnt64[c], pay);
        rank[e] = (int)(old >> 32);
    }
}

// ---------------- scan phase 1 (+ fused dinv) ----------------
__global__ __launch_bounds__(256) void k_scan1(const unsigned long long* __restrict__ cnt64,
                                               int* __restrict__ local,
                                               int* __restrict__ bsum,
                                               float* __restrict__ dinv, int n) {
    __shared__ int sm[256];
    int tid = threadIdx.x;
    int i = blockIdx.x * 256 + tid;
    unsigned long long cv = (i < n) ? cnt64[i] : 0ULL;
    int v = (int)(cv >> 32);
    if (i < n) {
        float deg = 1.0f + (float)(unsigned int)(cv & 0xffffffffULL) * FIXP_INV;
        dinv[i] = rsqrtf(deg);
    }
    sm[tid] = v;
    __syncthreads();
    for (int off = 1; off < 256; off <<= 1) {
        int add = (tid >= off) ? sm[tid - off] : 0;
        __syncthreads();
        sm[tid] += add;
        __syncthreads();
    }
    if (i < n) local[i] = sm[tid] - v;          // exclusive
    if (tid == 255) bsum[blockIdx.x] = sm[255]; // block total
}

__global__ __launch_bounds__(512) void k_scan2(int* bsum, int nb) {
    __shared__ int sm[512];
    int tid = threadIdx.x;
    int v = (tid < nb) ? bsum[tid] : 0;
    sm[tid] = v;
    __syncthreads();
    for (int off = 1; off < 512; off <<= 1) {
        int add = (tid >= off) ? sm[tid - off] : 0;
        __syncthreads();
        sm[tid] += add;
        __syncthreads();
    }
    if (tid < nb) bsum[tid] = sm[tid] - v;      // exclusive
}

__global__ __launch_bounds__(256) void k_scan3(const int* __restrict__ local,
                                               const int* __restrict__ bsum,
                                               int* __restrict__ start,
                                               int n, int E) {
    int i = blockIdx.x * 256 + threadIdx.x;
    if (i < n) start[i] = local[i] + bsum[blockIdx.x];
    if (i == 0) start[n] = E;
}

// ---------------- CSR fill (atomic-free) ----------------
__global__ __launch_bounds__(256) void k_fill(const int* __restrict__ rowi,
                                              const int* __restrict__ coli,
                                              const float* __restrict__ ew,
                                              const int* __restrict__ start,
                                              const int* __restrict__ rank,
                                              int2* __restrict__ csr, int E) {
    int e = blockIdx.x * 256 + threadIdx.x;
    if (e < E) {
        int c = coli[e];
        csr[start[c] + rank[e]] = make_int2(rowi[e], __float_as_int(ew[e]));
    }
}

// ------- GEMM: t_h = fp16( dinv .* (x @ W) ), 16 rows/block -------
__global__ __launch_bounds__(256) void k_gemm(const float* __restrict__ x,
                                              const float* __restrict__ W,
                                              const float* __restrict__ dinv,
                                              __half* __restrict__ th, int n) {
    __shared__ float Ws[64 * 64];
    __shared__ float xs[16][64];
    int tid = threadIdx.x;
    for (int i = tid; i < 4096; i += 256) Ws[i] = W[i];
    int row0 = blockIdx.x * 16;
    int nrows = min(16, n - row0);
    {
        const float4* xsrc = (const float4*)(x + (size_t)row0 * 64);
        float4* xdst = (float4*)&xs[0][0];
        if (tid < nrows * 16) xdst[tid] = xsrc[tid];
    }
    __syncthreads();
    int rl = tid >> 4;            // 0..15
    int f0 = (tid & 15) * 4;      // 0..60
    int row = row0 + rl;
    if (rl >= nrows) return;
    float a0 = 0.f, a1 = 0.f, a2 = 0.f, a3 = 0.f;
#pragma unroll
    for (int k = 0; k < 64; ++k) {
        float xv = xs[rl][k];
        const float* wr = &Ws[k * 64 + f0];
        a0 += xv * wr[0]; a1 += xv * wr[1]; a2 += xv * wr[2]; a3 += xv * wr[3];
    }
    float d = dinv[row];
    union { __half2 h2[2]; int2 i2; } u;
    u.h2[0] = __floats2half2_rn(a0 * d, a1 * d);
    u.h2[1] = __floats2half2_rn(a2 * d, a3 * d);
    ((int2*)th)[((size_t)row * 64 + f0) >> 2] = u.i2;
}

// ------- fused gather + post, half-wave edge streams -------
// One node per wave; lanes 0-31 (half 0) take even edges, lanes 32-63 odd.
// Each lane holds 2 features (float2). 4 chains/half => 8 gathers in flight.
// mode 0: ReLU+BN -> out ; mode 1: BN -> pooled (block-reduced atomics)
__global__ __launch_bounds__(256) void k_gather(const int2* __restrict__ csr,
                                                const int* __restrict__ start,
                                                const __half2* __restrict__ th2,
                                                const float* __restrict__ dinv,
                                                const float* __restrict__ bias,
                                                const float* __restrict__ gam,
                                                const float* __restrict__ bet,
                                                const float* __restrict__ mu,
                                                const float* __restrict__ var,
                                                float* __restrict__ out,
                                                const int* __restrict__ batch,
                                                float* __restrict__ pooled,
                                                int n, int mode) {
    __shared__ float vals[4][64];
    __shared__ int bids[4];
    int w = threadIdx.x >> 6;
    int lane = threadIdx.x & 63;
    int half = lane >> 5;        // 0 or 1: which edge stream
    int l = lane & 31;           // feature pair index (features 2l, 2l+1)
    int node = blockIdx.x * 4 + w;
    bool valid = node < n;
    float2 res = make_float2(0.f, 0.f);
    if (valid) {
        float2 a0 = make_float2(0.f, 0.f), a1 = a0, a2 = a0, a3 = a0;
        if (half == 0) {                       // self-loop (pre-scaled), once
            float2 sv = __half22float2(th2[(size_t)node * 32 + l]);
            a0 = sv;
        }
        int s = start[node], eend = start[node + 1];
        int e = s;
        for (; e + 7 < eend; e += 8) {         // 8 edges/iter, 4 chains/half
            int2 e0 = csr[e + 0 + half];
            int2 e1 = csr[e + 2 + half];
            int2 e2 = csr[e + 4 + half];
            int2 e3 = csr[e + 6 + half];
            float2 t0 = __half22float2(th2[(size_t)e0.x * 32 + l]);
            float2 t1 = __half22float2(th2[(size_t)e1.x * 32 + l]);
            float2 t2 = __half22float2(th2[(size_t)e2.x * 32 + l]);
            float2 t3 = __half22float2(th2[(size_t)e3.x * 32 + l]);
            float w0 = __int_as_float(e0.y), w1 = __int_as_float(e1.y);
            float w2 = __int_as_float(e2.y), w3 = __int_as_float(e3.y);
            a0.x = fmaf(w0, t0.x, a0.x); a0.y = fmaf(w0, t0.y, a0.y);
            a1.x = fmaf(w1, t1.x, a1.x); a1.y = fmaf(w1, t1.y, a1.y);
            a2.x = fmaf(w2, t2.x, a2.x); a2.y = fmaf(w2, t2.y, a2.y);
            a3.x = fmaf(w3, t3.x, a3.x); a3.y = fmaf(w3, t3.y, a3.y);
        }
        for (; e + half < eend; e += 2) {      // remainder, pairwise
            int2 ea = csr[e + half];
            float2 ta = __half22float2(th2[(size_t)ea.x * 32 + l]);
            float wa = __int_as_float(ea.y);
            a0.x = fmaf(wa, ta.x, a0.x); a0.y = fmaf(wa, ta.y, a0.y);
        }
        float2 acc;
        acc.x = (a0.x + a1.x) + (a2.x + a3.x);
        acc.y = (a0.y + a1.y) + (a2.y + a3.y);
        acc.x += __shfl_xor(acc.x, 32);        // merge the two halves
        acc.y += __shfl_xor(acc.y, 32);
        float d = dinv[node];
        float2 b2 = ((const float2*)bias)[l];
        float2 m2 = ((const float2*)mu)[l];
        float2 v2 = ((const float2*)var)[l];
        float2 G2 = ((const float2*)gam)[l];
        float2 B2 = ((const float2*)bet)[l];
        float r0 = d * acc.x + b2.x;
        float r1 = d * acc.y + b2.y;
        if (mode == 0) { r0 = fmaxf(r0, 0.f); r1 = fmaxf(r1, 0.f); }
        res.x = (r0 - m2.x) * rsqrtf(v2.x + BN_EPS) * G2.x + B2.x;
        res.y = (r1 - m2.y) * rsqrtf(v2.y + BN_EPS) * G2.y + B2.y;
    }
    if (mode == 0) {
        if (valid && half == 0)
            ((float2*)(out + (size_t)node * 64))[l] = res;
    } else {
        if (half == 0) ((float2*)(&vals[w][0]))[l] = res;  // res=0 if invalid
        if (lane == 0) bids[w] = valid ? batch[node] : -1;
        __syncthreads();
        if (w == 0) {
            int f = threadIdx.x;  // 0..63 (wave 0)
            float s2 = vals[0][f];
            int cur = bids[0];
            for (int i = 1; i < 4; ++i) {
                if (bids[i] == cur) {
                    s2 += vals[i][f];
                } else {
                    if (cur >= 0) fatomic_add(&pooled[cur * 64 + f], s2);
                    cur = bids[i];
                    s2 = vals[i][f];
                }
            }
            if (cur >= 0) fatomic_add(&pooled[cur * 64 + f], s2);
        }
    }
}

// ---------------- final: out[g] = ReLU(pooled[g]) @ Wfc + bfc ----------------
__global__ __launch_bounds__(128) void k_fc(const float* __restrict__ pooled,
                                            const float* __restrict__ Wfc,
                                            const float* __restrict__ bfc,
                                            float* __restrict__ out, int G) {
    int g = threadIdx.x;
    if (g >= G) return;
    float s = bfc[0];
#pragma unroll
    for (int f = 0; f < 64; ++f) s += fmaxf(pooled[g * 64 + f], 0.f) * Wfc[f];
    out[g] = s;
}

extern "C" void kernel_launch(void* const* d_in, const int* in_sizes, int n_in,
                              void* d_out, int out_size, void* d_ws, size_t ws_size,
                              hipStream_t stream) {
    const float* x    = (const float*)d_in[0];
    const int*   eidx = (const int*)d_in[1];
    const float* ew   = (const float*)d_in[2];
    const int*   batch= (const int*)d_in[3];
    const float* W1 = (const float*)d_in[4];
    const float* b1 = (const float*)d_in[5];
    const float* W2 = (const float*)d_in[6];
    const float* b2 = (const float*)d_in[7];
    const float* W3 = (const float*)d_in[8];
    const float* b3 = (const float*)d_in[9];
    const float* Wfc = (const float*)d_in[10];
    const float* bfc = (const float*)d_in[11];
    const float* g1 = (const float*)d_in[12];
    const float* be1 = (const float*)d_in[13];
    const float* m1 = (const float*)d_in[14];
    const float* v1 = (const float*)d_in[15];
    const float* g2 = (const float*)d_in[16];
    const float* be2 = (const float*)d_in[17];
    const float* m2 = (const float*)d_in[18];
    const float* v2 = (const float*)d_in[19];
    const float* g3 = (const float*)d_in[20];
    const float* be3 = (const float*)d_in[21];
    const float* m3 = (const float*)d_in[22];
    const float* v3 = (const float*)d_in[23];

    const int N = in_sizes[0] / 64;     // 100000
    const int E = in_sizes[1] / 2;      // 1600000
    const int G = out_size;             // 128
    const int* rowi = eidx;
    const int* coli = eidx + E;

    // -------- workspace layout (256B aligned) --------
    char* ws = (char*)d_ws;
    size_t off = 0;
    auto alloc = [&](size_t bytes) {
        char* p = ws + off;
        off += (bytes + 255) & ~(size_t)255;
        return p;
    };
    float* dinv   = (float*)alloc((size_t)N * 4);
    unsigned long long* cnt64 = (unsigned long long*)alloc((size_t)N * 8);
    int*   local  = (int*)  alloc((size_t)N * 4);
    int*   bsum   = (int*)  alloc(512 * 4);
    int*   start  = (int*)  alloc((size_t)(N + 1) * 4);
    int2*  csr    = (int2*) alloc((size_t)E * 8);
    __half* th    = (__half*)alloc((size_t)N * 64 * 2);
    float* h      = (float*)alloc((size_t)N * 64 * 4);
    float* pooled = (float*)alloc((size_t)G * 64 * 4);
    int*   rank   = (int*)h;   // rank (6.4MB) lives in h, dead until layer 1

    const int nblk = (N + 255) / 256;
    const int eblk = (E + 255) / 256;
    const int gblk = (N + 3) / 4;
    const int mblk = (N + 15) / 16;

    // -------- CSR build + normalization --------
    hipMemsetAsync(cnt64, 0, (size_t)N * 8, stream);
    k_hist_rank<<<eblk, 256, 0, stream>>>(coli, ew, cnt64, rank, E);
    k_scan1<<<nblk, 256, 0, stream>>>(cnt64, local, bsum, dinv, N);
    k_scan2<<<1, 512, 0, stream>>>(bsum, nblk);
    k_scan3<<<nblk, 256, 0, stream>>>(local, bsum, start, N, E);
    k_fill<<<eblk, 256, 0, stream>>>(rowi, coli, ew, start, rank, csr, E);

    // -------- layer 1 --------
    k_gemm<<<mblk, 256, 0, stream>>>(x, W1, dinv, th, N);
    k_gather<<<gblk, 256, 0, stream>>>(csr, start, (const __half2*)th, dinv,
                                       b1, g1, be1, m1, v1, h, batch, pooled, N, 0);
    // -------- layer 2 --------
    k_gemm<<<mblk, 256, 0, stream>>>(h, W2, dinv, th, N);
    k_gather<<<gblk, 256, 0, stream>>>(csr, start, (const __half2*)th, dinv,
                                       b2, g2, be2, m2, v2, h, batch, pooled, N, 0);
    // -------- layer 3 + pool --------
    k_gemm<<<mblk, 256, 0, stream>>>(h, W3, dinv, th, N);
    hipMemsetAsync(pooled, 0, (size_t)G * 64 * 4, stream);
    k_gather<<<gblk, 256, 0, stream>>>(csr, start, (const __half2*)th, dinv,
                                       b3, g3, be3, m3, v3, h, batch, pooled, N, 1);
    // -------- FC head --------
    k_fc<<<1, 128, 0, stream>>>(pooled, Wfc, bfc, (float*)d_out, G);
}

// Round 6
// 492.607 us; speedup vs baseline: 9.1603x; 1.0268x over previous
//
#include <hip/hip_runtime.h>
#include <hip/hip_fp16.h>

#define BN_EPS 1e-5f
#define FIXP 1048576.0f          // 2^20 fixed-point scale for edge weights
#define FIXP_INV (1.0f / 1048576.0f)

__device__ __forceinline__ float fatomic_add(float* p, float v) {
    return unsafeAtomicAdd(p, v);  // HW global_atomic_add_f32
}

// fma of a packed 4x fp16 row chunk into a float4 accumulator
__device__ __forceinline__ float4 fma8(int2 v, float wgt, float4 a) {
    float2 f0 = __half22float2(*(__half2*)&v.x);
    float2 f1 = __half22float2(*(__half2*)&v.y);
    a.x = fmaf(wgt, f0.x, a.x);
    a.y = fmaf(wgt, f0.y, a.y);
    a.z = fmaf(wgt, f1.x, a.z);
    a.w = fmaf(wgt, f1.y, a.w);
    return a;
}

// ------- histogram + deg + rank in ONE u64 atomic per edge -------
__global__ __launch_bounds__(256) void k_hist_rank(const int* __restrict__ col,
                                                   const float* __restrict__ ew,
                                                   unsigned long long* __restrict__ cnt64,
                                                   int* __restrict__ rank, int E) {
    int e = blockIdx.x * 256 + threadIdx.x;
    if (e < E) {
        int c = col[e];
        unsigned long long pay =
            (1ULL << 32) | (unsigned long long)__float2uint_rn(ew[e] * FIXP);
        unsigned long long old = atomicAdd(&cnt64[c], pay);
        rank[e] = (int)(old >> 32);
    }
}

// ---------------- scan phase 1 (+ fused dinv) ----------------
__global__ __launch_bounds__(256) void k_scan1(const unsigned long long* __restrict__ cnt64,
                                               int* __restrict__ local,
                                               int* __restrict__ bsum,
                                               float* __restrict__ dinv, int n) {
    __shared__ int sm[256];
    int tid = threadIdx.x;
    int i = blockIdx.x * 256 + tid;
    unsigned long long cv = (i < n) ? cnt64[i] : 0ULL;
    int v = (int)(cv >> 32);
    if (i < n) {
        float deg = 1.0f + (float)(unsigned int)(cv & 0xffffffffULL) * FIXP_INV;
        dinv[i] = rsqrtf(deg);
    }
    sm[tid] = v;
    __syncthreads();
    for (int off = 1; off < 256; off <<= 1) {
        int add = (tid >= off) ? sm[tid - off] : 0;
        __syncthreads();
        sm[tid] += add;
        __syncthreads();
    }
    if (i < n) local[i] = sm[tid] - v;          // exclusive
    if (tid == 255) bsum[blockIdx.x] = sm[255]; // block total
}

__global__ __launch_bounds__(512) void k_scan2(int* bsum, int nb) {
    __shared__ int sm[512];
    int tid = threadIdx.x;
    int v = (tid < nb) ? bsum[tid] : 0;
    sm[tid] = v;
    __syncthreads();
    for (int off = 1; off < 512; off <<= 1) {
        int add = (tid >= off) ? sm[tid - off] : 0;
        __syncthreads();
        sm[tid] += add;
        __syncthreads();
    }
    if (tid < nb) bsum[tid] = sm[tid] - v;      // exclusive
}

__global__ __launch_bounds__(256) void k_scan3(const int* __restrict__ local,
                                               const int* __restrict__ bsum,
                                               int* __restrict__ start,
                                               int n, int E) {
    int i = blockIdx.x * 256 + threadIdx.x;
    if (i < n) start[i] = local[i] + bsum[blockIdx.x];
    if (i == 0) start[n] = E;
}

// ---------------- CSR fill (atomic-free) ----------------
__global__ __launch_bounds__(256) void k_fill(const int* __restrict__ rowi,
                                              const int* __restrict__ coli,
                                              const float* __restrict__ ew,
                                              const int* __restrict__ start,
                                              const int* __restrict__ rank,
                                              int2* __restrict__ csr, int E) {
    int e = blockIdx.x * 256 + threadIdx.x;
    if (e < E) {
        int c = coli[e];
        csr[start[c] + rank[e]] = make_int2(rowi[e], __float_as_int(ew[e]));
    }
}

// ------- GEMM: t_h = fp16( dinv .* (x @ W) ), 16 rows/block -------
__global__ __launch_bounds__(256) void k_gemm(const float* __restrict__ x,
                                              const float* __restrict__ W,
                                              const float* __restrict__ dinv,
                                              __half* __restrict__ th, int n) {
    __shared__ float Ws[64 * 64];
    __shared__ float xs[16][64];
    int tid = threadIdx.x;
    for (int i = tid; i < 4096; i += 256) Ws[i] = W[i];
    int row0 = blockIdx.x * 16;
    int nrows = min(16, n - row0);
    {
        const float4* xsrc = (const float4*)(x + (size_t)row0 * 64);
        float4* xdst = (float4*)&xs[0][0];
        if (tid < nrows * 16) xdst[tid] = xsrc[tid];
    }
    __syncthreads();
    int rl = tid >> 4;            // 0..15
    int f0 = (tid & 15) * 4;      // 0..60
    int row = row0 + rl;
    if (rl >= nrows) return;
    float a0 = 0.f, a1 = 0.f, a2 = 0.f, a3 = 0.f;
#pragma unroll
    for (int k = 0; k < 64; ++k) {
        float xv = xs[rl][k];
        const float* wr = &Ws[k * 64 + f0];
        a0 += xv * wr[0]; a1 += xv * wr[1]; a2 += xv * wr[2]; a3 += xv * wr[3];
    }
    float d = dinv[row];
    union { __half2 h2[2]; int2 i2; } u;
    u.h2[0] = __floats2half2_rn(a0 * d, a1 * d);
    u.h2[1] = __floats2half2_rn(a2 * d, a3 * d);
    ((int2*)th)[((size_t)row * 64 + f0) >> 2] = u.i2;
}

// ------- fused gather + post, quarter-wave row loads -------
// One node per wave. Quarter q (16 lanes x 8B) owns edge stream e+4i+q with
// 4 chains => 16 rows (2 KiB) in flight per wave. Lane l holds feats 4l..4l+3.
// mode 0: ReLU+BN -> out ; mode 1: BN -> pooled (block-reduced atomics)
__global__ __launch_bounds__(256) void k_gather(const int2* __restrict__ csr,
                                                const int* __restrict__ start,
                                                const int2* __restrict__ th8,
                                                const float* __restrict__ dinv,
                                                const float* __restrict__ bias,
                                                const float* __restrict__ gam,
                                                const float* __restrict__ bet,
                                                const float* __restrict__ mu,
                                                const float* __restrict__ var,
                                                float* __restrict__ out,
                                                const int* __restrict__ batch,
                                                float* __restrict__ pooled,
                                                int n, int mode) {
    __shared__ float vals[4][64];
    __shared__ int bids[4];
    int w = threadIdx.x >> 6;
    int lane = threadIdx.x & 63;
    int q = lane >> 4;           // quarter: which edge sub-stream
    int l = lane & 15;           // feature quad index (features 4l..4l+3)
    int node = blockIdx.x * 4 + w;
    bool valid = node < n;
    float4 res = make_float4(0.f, 0.f, 0.f, 0.f);
    if (valid) {
        float4 a0 = make_float4(0.f, 0.f, 0.f, 0.f), a1 = a0, a2 = a0, a3 = a0;
        if (q == 0)              // self-loop (pre-scaled), once
            a0 = fma8(th8[(size_t)node * 16 + l], 1.0f, a0);
        int s = start[node], eend = start[node + 1];
        int e = s;
        for (; e + 15 < eend; e += 16) {   // 16 edges/iter, 4 chains/quarter
            int2 e0 = csr[e + q];
            int2 e1 = csr[e + 4 + q];
            int2 e2 = csr[e + 8 + q];
            int2 e3 = csr[e + 12 + q];
            int2 r0 = th8[(size_t)e0.x * 16 + l];
            int2 r1 = th8[(size_t)e1.x * 16 + l];
            int2 r2 = th8[(size_t)e2.x * 16 + l];
            int2 r3 = th8[(size_t)e3.x * 16 + l];
            a0 = fma8(r0, __int_as_float(e0.y), a0);
            a1 = fma8(r1, __int_as_float(e1.y), a1);
            a2 = fma8(r2, __int_as_float(e2.y), a2);
            a3 = fma8(r3, __int_as_float(e3.y), a3);
        }
        for (; e + q < eend; e += 4) {     // remainder: 4 edges/iter
            int2 ea = csr[e + q];
            int2 ra = th8[(size_t)ea.x * 16 + l];
            a0 = fma8(ra, __int_as_float(ea.y), a0);
        }
        float4 acc;
        acc.x = (a0.x + a1.x) + (a2.x + a3.x);
        acc.y = (a0.y + a1.y) + (a2.y + a3.y);
        acc.z = (a0.z + a1.z) + (a2.z + a3.z);
        acc.w = (a0.w + a1.w) + (a2.w + a3.w);
        acc.x += __shfl_xor(acc.x, 16);    // merge quarters
        acc.y += __shfl_xor(acc.y, 16);
        acc.z += __shfl_xor(acc.z, 16);
        acc.w += __shfl_xor(acc.w, 16);
        acc.x += __shfl_xor(acc.x, 32);
        acc.y += __shfl_xor(acc.y, 32);
        acc.z += __shfl_xor(acc.z, 32);
        acc.w += __shfl_xor(acc.w, 32);
        float d = dinv[node];
        float4 b4 = ((const float4*)bias)[l];
        float4 m4 = ((const float4*)mu)[l];
        float4 v4 = ((const float4*)var)[l];
        float4 G4 = ((const float4*)gam)[l];
        float4 B4 = ((const float4*)bet)[l];
        float r0 = d * acc.x + b4.x;
        float r1 = d * acc.y + b4.y;
        float r2 = d * acc.z + b4.z;
        float r3 = d * acc.w + b4.w;
        if (mode == 0) {
            r0 = fmaxf(r0, 0.f); r1 = fmaxf(r1, 0.f);
            r2 = fmaxf(r2, 0.f); r3 = fmaxf(r3, 0.f);
        }
        res.x = (r0 - m4.x) * rsqrtf(v4.x + BN_EPS) * G4.x + B4.x;
        res.y = (r1 - m4.y) * rsqrtf(v4.y + BN_EPS) * G4.y + B4.y;
        res.z = (r2 - m4.z) * rsqrtf(v4.z + BN_EPS) * G4.z + B4.z;
        res.w = (r3 - m4.w) * rsqrtf(v4.w + BN_EPS) * G4.w + B4.w;
    }
    if (mode == 0) {
        if (valid && q == 0)
            ((float4*)(out + (size_t)node * 64))[l] = res;
    } else {
        if (q == 0) ((float4*)(&vals[w][0]))[l] = res;   // res=0 if invalid
        if (lane == 0) bids[w] = valid ? batch[node] : -1;
        __syncthreads();
        if (w == 0) {
            int f = threadIdx.x;  // 0..63 (wave 0)
            float s2 = vals[0][f];
            int cur = bids[0];
            for (int i = 1; i < 4; ++i) {
                if (bids[i] == cur) {
                    s2 += vals[i][f];
                } else {
                    if (cur >= 0) fatomic_add(&pooled[cur * 64 + f], s2);
                    cur = bids[i];
                    s2 = vals[i][f];
                }
            }
            if (cur >= 0) fatomic_add(&pooled[cur * 64 + f], s2);
        }
    }
}

// ---------------- final: out[g] = ReLU(pooled[g]) @ Wfc + bfc ----------------
__global__ __launch_bounds__(128) void k_fc(const float* __restrict__ pooled,
                                            const float* __restrict__ Wfc,
                                            const float* __restrict__ bfc,
                                            float* __restrict__ out, int G) {
    int g = threadIdx.x;
    if (g >= G) return;
    float s = bfc[0];
#pragma unroll
    for (int f = 0; f < 64; ++f) s += fmaxf(pooled[g * 64 + f], 0.f) * Wfc[f];
    out[g] = s;
}

extern "C" void kernel_launch(void* const* d_in, const int* in_sizes, int n_in,
                              void* d_out, int out_size, void* d_ws, size_t ws_size,
                              hipStream_t stream) {
    const float* x    = (const float*)d_in[0];
    const int*   eidx = (const int*)d_in[1];
    const float* ew   = (const float*)d_in[2];
    const int*   batch= (const int*)d_in[3];
    const float* W1 = (const float*)d_in[4];
    const float* b1 = (const float*)d_in[5];
    const float* W2 = (const float*)d_in[6];
    const float* b2 = (const float*)d_in[7];
    const float* W3 = (const float*)d_in[8];
    const float* b3 = (const float*)d_in[9];
    const float* Wfc = (const float*)d_in[10];
    const float* bfc = (const float*)d_in[11];
    const float* g1 = (const float*)d_in[12];
    const float* be1 = (const float*)d_in[13];
    const float* m1 = (const float*)d_in[14];
    const float* v1 = (const float*)d_in[15];
    const float* g2 = (const float*)d_in[16];
    const float* be2 = (const float*)d_in[17];
    const float* m2 = (const float*)d_in[18];
    const float* v2 = (const float*)d_in[19];
    const float* g3 = (const float*)d_in[20];
    const float* be3 = (const float*)d_in[21];
    const float* m3 = (const float*)d_in[22];
    const float* v3 = (const float*)d_in[23];

    const int N = in_sizes[0] / 64;     // 100000
    const int E = in_sizes[1] / 2;      // 1600000
    const int G = out_size;             // 128
    const int* rowi = eidx;
    const int* coli = eidx + E;

    // -------- workspace layout (256B aligned) --------
    char* ws = (char*)d_ws;
    size_t off = 0;
    auto alloc = [&](size_t bytes) {
        char* p = ws + off;
        off += (bytes + 255) & ~(size_t)255;
        return p;
    };
    float* dinv   = (float*)alloc((size_t)N * 4);
    unsigned long long* cnt64 = (unsigned long long*)alloc((size_t)N * 8);
    int*   local  = (int*)  alloc((size_t)N * 4);
    int*   bsum   = (int*)  alloc(512 * 4);
    int*   start  = (int*)  alloc((size_t)(N + 1) * 4);
    int2*  csr    = (int2*) alloc((size_t)E * 8);
    __half* th    = (__half*)alloc((size_t)N * 64 * 2);
    float* h      = (float*)alloc((size_t)N * 64 * 4);
    float* pooled = (float*)alloc((size_t)G * 64 * 4);
    int*   rank   = (int*)h;   // rank (6.4MB) lives in h, dead until layer 1

    const int nblk = (N + 255) / 256;
    const int eblk = (E + 255) / 256;
    const int gblk = (N + 3) / 4;
    const int mblk = (N + 15) / 16;

    // -------- CSR build + normalization --------
    hipMemsetAsync(cnt64, 0, (size_t)N * 8, stream);
    k_hist_rank<<<eblk, 256, 0, stream>>>(coli, ew, cnt64, rank, E);
    k_scan1<<<nblk, 256, 0, stream>>>(cnt64, local, bsum, dinv, N);
    k_scan2<<<1, 512, 0, stream>>>(bsum, nblk);
    k_scan3<<<nblk, 256, 0, stream>>>(local, bsum, start, N, E);
    k_fill<<<eblk, 256, 0, stream>>>(rowi, coli, ew, start, rank, csr, E);

    // -------- layer 1 --------
    k_gemm<<<mblk, 256, 0, stream>>>(x, W1, dinv, th, N);
    k_gather<<<gblk, 256, 0, stream>>>(csr, start, (const int2*)th, dinv,
                                       b1, g1, be1, m1, v1, h, batch, pooled, N, 0);
    // -------- layer 2 --------
    k_gemm<<<mblk, 256, 0, stream>>>(h, W2, dinv, th, N);
    k_gather<<<gblk, 256, 0, stream>>>(csr, start, (const int2*)th, dinv,
                                       b2, g2, be2, m2, v2, h, batch, pooled, N, 0);
    // -------- layer 3 + pool --------
    k_gemm<<<mblk, 256, 0, stream>>>(h, W3, dinv, th, N);
    hipMemsetAsync(pooled, 0, (size_t)G * 64 * 4, stream);
    k_gather<<<gblk, 256, 0, stream>>>(csr, start, (const int2*)th, dinv,
                                       b3, g3, be3, m3, v3, h, batch, pooled, N, 1);
    // -------- FC head --------
    k_fc<<<1, 128, 0, stream>>>(pooled, Wfc, bfc, (float*)d_out, G);
}